// Round 1
// baseline (765.786 us; speedup 1.0000x reference)
//
#include <hip/hip_runtime.h>

#define S_LEN 2048
#define D_DIM 2048
#define NH 16
#define HD 128
#define NB 2
#define NROW (NB * S_LEN)  // 4096

typedef unsigned short bf16;
typedef __attribute__((ext_vector_type(8))) short bf16x8;
typedef __attribute__((ext_vector_type(4))) float f32x4;
typedef __attribute__((address_space(3))) unsigned int as3u;
typedef __attribute__((address_space(1))) unsigned int as1u;

__device__ __forceinline__ void gload16(const void* g, void* l) {
  __builtin_amdgcn_global_load_lds((const as1u*)g, (as3u*)l, 16, 0, 0);
}

__device__ __forceinline__ unsigned short f2bf(float f) {
  unsigned u = __builtin_bit_cast(unsigned, f);
  u += 0x7FFFu + ((u >> 16) & 1u);
  return (unsigned short)(u >> 16);
}
__device__ __forceinline__ float bf2f(unsigned short b) {
  return __builtin_bit_cast(float, (unsigned)b << 16);
}

// ---------------- small prep kernels ----------------

// cos/sin table: tab[s*64 + i] = (cos(s*invf_i), sin(s*invf_i))
__global__ void rope_table_k(float2* __restrict__ tab) {
  int i = blockIdx.x * 256 + threadIdx.x;  // S*64 = 131072 threads
  int s = i >> 6, d = i & 63;
  float invf = powf(10000.0f, -(float)d * (1.0f / 64.0f));
  float ang = (float)s * invf;
  tab[i] = make_float2(cosf(ang), sinf(ang));
}

// f32 -> bf16, 4 elements/thread
__global__ void convert_x_k(const float* __restrict__ src, bf16* __restrict__ dst) {
  int i = (blockIdx.x * 256 + threadIdx.x) * 4;
  float4 v = *(const float4*)(src + i);
  ushort4 w;
  w.x = f2bf(v.x); w.y = f2bf(v.y); w.z = f2bf(v.z); w.w = f2bf(v.w);
  *(ushort4*)(dst + i) = w;
}

// W [D][D] f32 -> Wt [D][D] bf16 with Wt[n][k] = W[k][n]
__global__ void transpose_w_k(const float* __restrict__ W, bf16* __restrict__ Wt) {
  __shared__ float t[64][65];
  int c0 = blockIdx.x * 64, r0 = blockIdx.y * 64;
  int tx = threadIdx.x & 63, ty = threadIdx.x >> 6;  // 4 rows/pass
#pragma unroll
  for (int i = 0; i < 16; ++i)
    t[ty + i * 4][tx] = W[(size_t)(r0 + ty + i * 4) * D_DIM + c0 + tx];
  __syncthreads();
#pragma unroll
  for (int i = 0; i < 16; ++i)
    Wt[(size_t)(c0 + ty + i * 4) * D_DIM + r0 + tx] = f2bf(t[tx][ty + i * 4]);
}

// V [b*S+s][h*128+d] bf16 -> Vt [bh][d][s] bf16
__global__ void transpose_v_k(const bf16* __restrict__ V, bf16* __restrict__ Vt) {
  __shared__ bf16 t[64][65];
  int bh = blockIdx.z;
  int b = bh >> 4, h = bh & 15;
  int s0 = blockIdx.x * 64, d0 = blockIdx.y * 64;
  int tx = threadIdx.x & 63, ty = threadIdx.x >> 6;
  const bf16* src = V + (size_t)(b * S_LEN + s0) * D_DIM + h * HD + d0;
#pragma unroll
  for (int i = 0; i < 16; ++i)
    t[ty + i * 4][tx] = src[(size_t)(ty + i * 4) * D_DIM + tx];
  __syncthreads();
  bf16* dst = Vt + ((size_t)bh * HD + d0) * S_LEN + s0;
#pragma unroll
  for (int i = 0; i < 16; ++i)
    dst[(size_t)(ty + i * 4) * S_LEN + tx] = t[tx][ty + i * 4];
}

// RoPE in-place on Q and K; one thread per (row, head, d<64)
__global__ void rope_apply_k(bf16* __restrict__ q, bf16* __restrict__ k,
                             const float2* __restrict__ tab) {
  int i = blockIdx.x * 256 + threadIdx.x;  // NROW*NH*64
  int d = i & 63;
  int t = i >> 6;
  int h = t & 15;
  int row = t >> 4;          // b*S + s
  int s = row & (S_LEN - 1);
  float2 cs = tab[s * 64 + d];
  size_t base = (size_t)row * D_DIM + h * HD + d;
  float x1 = bf2f(q[base]), x2 = bf2f(q[base + 64]);
  q[base]      = f2bf(x1 * cs.x - x2 * cs.y);
  q[base + 64] = f2bf(x2 * cs.x + x1 * cs.y);
  float y1 = bf2f(k[base]), y2 = bf2f(k[base + 64]);
  k[base]      = f2bf(y1 * cs.x - y2 * cs.y);
  k[base + 64] = f2bf(y2 * cs.x + y1 * cs.y);
}

// ---------------- GEMM: C[M][N] = A[M][K] @ Bt[N][K]^T ----------------
// 128x128 tile, BK=32, 4 waves (each 64x64), mfma 16x16x32 bf16.

__device__ __forceinline__ void storec(bf16* p, float v) { *p = f2bf(v); }
__device__ __forceinline__ void storec(float* p, float v) { *p = v; }

template <typename OutT>
__global__ __launch_bounds__(256) void gemm_bt_k(
    const bf16* __restrict__ A, const bf16* __restrict__ Bt,
    OutT* __restrict__ C, int M, int N, int K) {
  __shared__ bf16 As[128 * 32];
  __shared__ bf16 Bs[128 * 32];
  const int tid = threadIdx.x;
  const int lane = tid & 63;
  const int wid = tid >> 6;
  const int bm = blockIdx.y * 128;
  const int bn = blockIdx.x * 128;
  const int wr = (wid >> 1) * 64;
  const int wc = (wid & 1) * 64;
  const int lr = lane & 15;
  const int kg = lane >> 4;

  f32x4 acc[4][4] = {};

  const int c0 = wid * 2;
  const int srow = lane >> 2;
  const int scol = (lane & 3) * 8;
  const bf16* Ap0 = A + (size_t)(bm + c0 * 16 + srow) * K + scol;
  const bf16* Ap1 = Ap0 + (size_t)16 * K;
  const bf16* Bp0 = Bt + (size_t)(bn + c0 * 16 + srow) * K + scol;
  const bf16* Bp1 = Bp0 + (size_t)16 * K;
  bf16* Asd0 = &As[c0 * 512];
  bf16* Asd1 = &As[(c0 + 1) * 512];
  bf16* Bsd0 = &Bs[c0 * 512];
  bf16* Bsd1 = &Bs[(c0 + 1) * 512];

  for (int k0 = 0; k0 < K; k0 += 32) {
    __syncthreads();
    gload16(Ap0 + k0, Asd0);
    gload16(Ap1 + k0, Asd1);
    gload16(Bp0 + k0, Bsd0);
    gload16(Bp1 + k0, Bsd1);
    __syncthreads();
    bf16x8 a[4], b[4];
#pragma unroll
    for (int m = 0; m < 4; ++m)
      a[m] = *(const bf16x8*)&As[(wr + m * 16 + lr) * 32 + kg * 8];
#pragma unroll
    for (int n = 0; n < 4; ++n)
      b[n] = *(const bf16x8*)&Bs[(wc + n * 16 + lr) * 32 + kg * 8];
#pragma unroll
    for (int m = 0; m < 4; ++m)
#pragma unroll
      for (int n = 0; n < 4; ++n)
        acc[m][n] = __builtin_amdgcn_mfma_f32_16x16x32_bf16(a[m], b[n], acc[m][n], 0, 0, 0);
  }

#pragma unroll
  for (int m = 0; m < 4; ++m) {
    int row0 = bm + wr + m * 16 + kg * 4;
#pragma unroll
    for (int n = 0; n < 4; ++n) {
      int col = bn + wc + n * 16 + lr;
#pragma unroll
      for (int r = 0; r < 4; ++r)
        storec(&C[(size_t)(row0 + r) * N + col], acc[m][n][r]);
    }
  }
}

// ---------------- causal flash attention ----------------
// grid (S/64, B*H); 4 waves/block; each wave owns 16 q-rows.
__global__ __launch_bounds__(256) void flash_attn_k(
    const bf16* __restrict__ Q, const bf16* __restrict__ Kb,
    const bf16* __restrict__ Vt, bf16* __restrict__ O) {
  __shared__ bf16 Plds[4][16 * 32];
  const int tid = threadIdx.x;
  const int lane = tid & 63;
  const int wid = tid >> 6;
  const int lr = lane & 15;
  const int kg = lane >> 4;
  const int bh = blockIdx.y;
  const int b = bh >> 4;
  const int h = bh & 15;
  const int q0 = blockIdx.x * 64 + wid * 16;

  // hoist Q fragments (16 rows x 128 HD) to registers
  const bf16* qptr = Q + (size_t)(b * S_LEN + q0 + lr) * D_DIM + h * HD + kg * 8;
  bf16x8 aq[4];
#pragma unroll
  for (int kk = 0; kk < 4; ++kk) aq[kk] = *(const bf16x8*)(qptr + kk * 32);

  f32x4 o[8] = {};
  float m_run[4], l_run[4];
#pragma unroll
  for (int r = 0; r < 4; ++r) { m_run[r] = -3.0e38f; l_run[r] = 0.f; }

  const float scale = 0.08838834764831845f;  // 128^-0.5
  const int kv_end = q0 + 16;
  const bf16* Kbase = Kb + (size_t)(b * S_LEN) * D_DIM + h * HD + kg * 8;
  const bf16* Vbase = Vt + (size_t)bh * HD * S_LEN + kg * 8;

  for (int kv0 = 0; kv0 < kv_end; kv0 += 32) {
    f32x4 s0 = {}, s1 = {};
    {
      const bf16* kp0 = Kbase + (size_t)(kv0 + lr) * D_DIM;
      const bf16* kp1 = Kbase + (size_t)(kv0 + 16 + lr) * D_DIM;
#pragma unroll
      for (int kk = 0; kk < 4; ++kk) {
        bf16x8 bk0 = *(const bf16x8*)(kp0 + kk * 32);
        bf16x8 bk1 = *(const bf16x8*)(kp1 + kk * 32);
        s0 = __builtin_amdgcn_mfma_f32_16x16x32_bf16(aq[kk], bk0, s0, 0, 0, 0);
        s1 = __builtin_amdgcn_mfma_f32_16x16x32_bf16(aq[kk], bk1, s1, 0, 0, 0);
      }
    }
    // scale + causal mask. element (q = q0+kg*4+r, kv = kv0+t*16+lr)
    float p[2][4];
    const bool edge = (kv0 + 31 > q0);
#pragma unroll
    for (int t = 0; t < 2; ++t)
#pragma unroll
      for (int r = 0; r < 4; ++r) {
        float v = (t == 0 ? s0[r] : s1[r]) * scale;
        if (edge && (kv0 + t * 16 + lr > q0 + kg * 4 + r)) v = -1.0e30f;
        p[t][r] = v;
      }
    // row max over 16 lanes (xor on low 4 bits)
    float mt[4];
#pragma unroll
    for (int r = 0; r < 4; ++r) mt[r] = fmaxf(p[0][r], p[1][r]);
#pragma unroll
    for (int off = 1; off < 16; off <<= 1)
#pragma unroll
      for (int r = 0; r < 4; ++r) mt[r] = fmaxf(mt[r], __shfl_xor(mt[r], off));
    float mnew[4], alpha[4], rs[4];
#pragma unroll
    for (int r = 0; r < 4; ++r) {
      mnew[r] = fmaxf(m_run[r], mt[r]);
      alpha[r] = __expf(m_run[r] - mnew[r]);
      rs[r] = 0.f;
    }
#pragma unroll
    for (int t = 0; t < 2; ++t)
#pragma unroll
      for (int r = 0; r < 4; ++r) {
        p[t][r] = __expf(p[t][r] - mnew[r]);
        rs[r] += p[t][r];
      }
#pragma unroll
    for (int off = 1; off < 16; off <<= 1)
#pragma unroll
      for (int r = 0; r < 4; ++r) rs[r] += __shfl_xor(rs[r], off);
#pragma unroll
    for (int r = 0; r < 4; ++r) {
      l_run[r] = l_run[r] * alpha[r] + rs[r];
      m_run[r] = mnew[r];
    }
#pragma unroll
    for (int n = 0; n < 8; ++n)
#pragma unroll
      for (int r = 0; r < 4; ++r) o[n][r] *= alpha[r];
    // P -> LDS (C-layout write), read back in A-layout
#pragma unroll
    for (int t = 0; t < 2; ++t)
#pragma unroll
      for (int r = 0; r < 4; ++r)
        Plds[wid][(kg * 4 + r) * 32 + t * 16 + lr] = f2bf(p[t][r]);
    bf16x8 ap = *(const bf16x8*)&Plds[wid][lr * 32 + kg * 8];
#pragma unroll
    for (int n = 0; n < 8; ++n) {
      bf16x8 bv = *(const bf16x8*)(Vbase + (size_t)(n * 16 + lr) * S_LEN + kv0);
      o[n] = __builtin_amdgcn_mfma_f32_16x16x32_bf16(ap, bv, o[n], 0, 0, 0);
    }
  }
  // epilogue: normalize + store
#pragma unroll
  for (int r = 0; r < 4; ++r) {
    float inv = 1.0f / l_run[r];
    size_t obase = (size_t)(b * S_LEN + q0 + kg * 4 + r) * D_DIM + h * HD;
#pragma unroll
    for (int n = 0; n < 8; ++n)
      O[obase + n * 16 + lr] = f2bf(o[n][r] * inv);
  }
}

// ---------------- launch ----------------

extern "C" void kernel_launch(void* const* d_in, const int* in_sizes, int n_in,
                              void* d_out, int out_size, void* d_ws, size_t ws_size,
                              hipStream_t stream) {
  (void)in_sizes; (void)n_in; (void)out_size; (void)ws_size;
  const float* x  = (const float*)d_in[0];
  const float* wq = (const float*)d_in[1];
  const float* wk = (const float*)d_in[2];
  const float* wv = (const float*)d_in[3];
  const float* wo = (const float*)d_in[4];
  // d_in[5] = mask: exactly causal, implemented analytically in flash_attn_k.
  float* out = (float*)d_out;

  char* ws = (char*)d_ws;
  const size_t MB = 1u << 20;
  bf16* xb  = (bf16*)(ws + 0 * MB);    // 16MB, reused as O after V GEMM
  bf16* Ob  = xb;
  bf16* wTq = (bf16*)(ws + 16 * MB);   // 8MB each
  bf16* wTk = (bf16*)(ws + 24 * MB);
  bf16* wTv = (bf16*)(ws + 32 * MB);
  bf16* wTo = (bf16*)(ws + 40 * MB);
  bf16* Qb  = (bf16*)(ws + 48 * MB);   // 16MB
  bf16* Kb  = (bf16*)(ws + 64 * MB);   // 16MB
  bf16* Vb  = (bf16*)(ws + 80 * MB);   // 16MB
  bf16* Vtb = (bf16*)(ws + 96 * MB);   // 16MB
  float2* tab = (float2*)(ws + 112 * MB);  // 1MB

  rope_table_k<<<512, 256, 0, stream>>>(tab);
  convert_x_k<<<8192, 256, 0, stream>>>(x, xb);
  dim3 tg(32, 32);
  transpose_w_k<<<tg, 256, 0, stream>>>(wq, wTq);
  transpose_w_k<<<tg, 256, 0, stream>>>(wk, wTk);
  transpose_w_k<<<tg, 256, 0, stream>>>(wv, wTv);
  transpose_w_k<<<tg, 256, 0, stream>>>(wo, wTo);

  dim3 gg(D_DIM / 128, NROW / 128);  // (16, 32)
  gemm_bt_k<bf16><<<gg, 256, 0, stream>>>(xb, wTq, Qb, NROW, D_DIM, D_DIM);
  gemm_bt_k<bf16><<<gg, 256, 0, stream>>>(xb, wTk, Kb, NROW, D_DIM, D_DIM);
  gemm_bt_k<bf16><<<gg, 256, 0, stream>>>(xb, wTv, Vb, NROW, D_DIM, D_DIM);

  rope_apply_k<<<16384, 256, 0, stream>>>(Qb, Kb, tab);
  transpose_v_k<<<dim3(32, 2, 32), 256, 0, stream>>>(Vb, Vtb);

  flash_attn_k<<<dim3(S_LEN / 64, NB * NH), 256, 0, stream>>>(Qb, Kb, Vtb, Ob);

  gemm_bt_k<float><<<gg, 256, 0, stream>>>(Ob, wTo, out, NROW, D_DIM, D_DIM);
}

// Round 2
// 414.300 us; speedup vs baseline: 1.8484x; 1.8484x over previous
//
#include <hip/hip_runtime.h>

#define S_LEN 2048
#define D_DIM 2048
#define NH 16
#define HD 128
#define NB 2
#define NROW (NB * S_LEN)  // 4096

typedef unsigned short bf16;
typedef __attribute__((ext_vector_type(8))) short bf16x8;
typedef __attribute__((ext_vector_type(4))) float f32x4;
typedef __attribute__((ext_vector_type(16))) float f32x16;
typedef __attribute__((address_space(3))) unsigned int as3u;
typedef __attribute__((address_space(1))) unsigned int as1u;

__device__ __forceinline__ void gload16(const void* g, void* l) {
  __builtin_amdgcn_global_load_lds((const as1u*)g, (as3u*)l, 16, 0, 0);
}

__device__ __forceinline__ unsigned short f2bf(float f) {
  unsigned u = __builtin_bit_cast(unsigned, f);
  u += 0x7FFFu + ((u >> 16) & 1u);
  return (unsigned short)(u >> 16);
}
__device__ __forceinline__ float bf2f(unsigned short b) {
  return __builtin_bit_cast(float, (unsigned)b << 16);
}
__device__ __forceinline__ unsigned cvtpk(float lo, float hi) {
  unsigned r;
  asm("v_cvt_pk_bf16_f32 %0, %1, %2" : "=v"(r) : "v"(lo), "v"(hi));
  return r;
}

// ---------------- small prep kernels ----------------

__global__ void rope_table_k(float2* __restrict__ tab) {
  int i = blockIdx.x * 256 + threadIdx.x;  // S*64
  int s = i >> 6, d = i & 63;
  float invf = powf(10000.0f, -(float)d * (1.0f / 64.0f));
  float ang = (float)s * invf;
  tab[i] = make_float2(cosf(ang), sinf(ang));
}

__global__ void convert_x_k(const float* __restrict__ src, bf16* __restrict__ dst) {
  int i = (blockIdx.x * 256 + threadIdx.x) * 4;
  float4 v = *(const float4*)(src + i);
  ushort4 w;
  w.x = f2bf(v.x); w.y = f2bf(v.y); w.z = f2bf(v.z); w.w = f2bf(v.w);
  *(ushort4*)(dst + i) = w;
}

__global__ void transpose_w_k(const float* __restrict__ W, bf16* __restrict__ Wt) {
  __shared__ float t[64][65];
  int c0 = blockIdx.x * 64, r0 = blockIdx.y * 64;
  int tx = threadIdx.x & 63, ty = threadIdx.x >> 6;
#pragma unroll
  for (int i = 0; i < 16; ++i)
    t[ty + i * 4][tx] = W[(size_t)(r0 + ty + i * 4) * D_DIM + c0 + tx];
  __syncthreads();
#pragma unroll
  for (int i = 0; i < 16; ++i)
    Wt[(size_t)(c0 + ty + i * 4) * D_DIM + r0 + tx] = f2bf(t[tx][ty + i * 4]);
}

__global__ void transpose_v_k(const bf16* __restrict__ V, bf16* __restrict__ Vt) {
  __shared__ bf16 t[64][65];
  int bh = blockIdx.z;
  int b = bh >> 4, h = bh & 15;
  int s0 = blockIdx.x * 64, d0 = blockIdx.y * 64;
  int tx = threadIdx.x & 63, ty = threadIdx.x >> 6;
  const bf16* src = V + (size_t)(b * S_LEN + s0) * D_DIM + h * HD + d0;
#pragma unroll
  for (int i = 0; i < 16; ++i)
    t[ty + i * 4][tx] = src[(size_t)(ty + i * 4) * D_DIM + tx];
  __syncthreads();
  bf16* dst = Vt + ((size_t)bh * HD + d0) * S_LEN + s0;
#pragma unroll
  for (int i = 0; i < 16; ++i)
    dst[(size_t)(ty + i * 4) * S_LEN + tx] = t[tx][ty + i * 4];
}

// RoPE in-place on Q and K; attention scale (128^-0.5) folded into Q here.
__global__ void rope_apply_k(bf16* __restrict__ q, bf16* __restrict__ k,
                             const float2* __restrict__ tab) {
  int i = blockIdx.x * 256 + threadIdx.x;  // NROW*NH*64
  int d = i & 63;
  int t = i >> 6;
  int h = t & 15;
  int row = t >> 4;
  int s = row & (S_LEN - 1);
  const float scale = 0.08838834764831845f;
  float2 cs = tab[s * 64 + d];
  size_t base = (size_t)row * D_DIM + h * HD + d;
  float x1 = bf2f(q[base]), x2 = bf2f(q[base + 64]);
  q[base]      = f2bf((x1 * cs.x - x2 * cs.y) * scale);
  q[base + 64] = f2bf((x2 * cs.x + x1 * cs.y) * scale);
  float y1 = bf2f(k[base]), y2 = bf2f(k[base + 64]);
  k[base]      = f2bf(y1 * cs.x - y2 * cs.y);
  k[base + 64] = f2bf(y2 * cs.x + y1 * cs.y);
}

// ---------------- GEMM: C[M][N] = A[M][K] @ Bt[N][K]^T ----------------

__device__ __forceinline__ void storec(bf16* p, float v) { *p = f2bf(v); }
__device__ __forceinline__ void storec(float* p, float v) { *p = v; }

template <typename OutT>
__global__ __launch_bounds__(256) void gemm_bt_k(
    const bf16* __restrict__ A, const bf16* __restrict__ Bt,
    OutT* __restrict__ C, int M, int N, int K) {
  __shared__ bf16 As[128 * 32];
  __shared__ bf16 Bs[128 * 32];
  const int tid = threadIdx.x;
  const int lane = tid & 63;
  const int wid = tid >> 6;
  const int bm = blockIdx.y * 128;
  const int bn = blockIdx.x * 128;
  const int wr = (wid >> 1) * 64;
  const int wc = (wid & 1) * 64;
  const int lr = lane & 15;
  const int kg = lane >> 4;

  f32x4 acc[4][4] = {};

  const int c0 = wid * 2;
  const int srow = lane >> 2;
  const int scol = (lane & 3) * 8;
  const bf16* Ap0 = A + (size_t)(bm + c0 * 16 + srow) * K + scol;
  const bf16* Ap1 = Ap0 + (size_t)16 * K;
  const bf16* Bp0 = Bt + (size_t)(bn + c0 * 16 + srow) * K + scol;
  const bf16* Bp1 = Bp0 + (size_t)16 * K;
  bf16* Asd0 = &As[c0 * 512];
  bf16* Asd1 = &As[(c0 + 1) * 512];
  bf16* Bsd0 = &Bs[c0 * 512];
  bf16* Bsd1 = &Bs[(c0 + 1) * 512];

  for (int k0 = 0; k0 < K; k0 += 32) {
    __syncthreads();
    gload16(Ap0 + k0, Asd0);
    gload16(Ap1 + k0, Asd1);
    gload16(Bp0 + k0, Bsd0);
    gload16(Bp1 + k0, Bsd1);
    __syncthreads();
    bf16x8 a[4], b[4];
#pragma unroll
    for (int m = 0; m < 4; ++m)
      a[m] = *(const bf16x8*)&As[(wr + m * 16 + lr) * 32 + kg * 8];
#pragma unroll
    for (int n = 0; n < 4; ++n)
      b[n] = *(const bf16x8*)&Bs[(wc + n * 16 + lr) * 32 + kg * 8];
#pragma unroll
    for (int m = 0; m < 4; ++m)
#pragma unroll
      for (int n = 0; n < 4; ++n)
        acc[m][n] = __builtin_amdgcn_mfma_f32_16x16x32_bf16(a[m], b[n], acc[m][n], 0, 0, 0);
  }

#pragma unroll
  for (int m = 0; m < 4; ++m) {
    int row0 = bm + wr + m * 16 + kg * 4;
#pragma unroll
    for (int n = 0; n < 4; ++n) {
      int col = bn + wc + n * 16 + lr;
#pragma unroll
      for (int r = 0; r < 4; ++r)
        storec(&C[(size_t)(row0 + r) * N + col], acc[m][n][r]);
    }
  }
}

// ---------------- causal flash attention, 32x32 swapped layout ----------------
// Block: 128 q rows (4 waves x 32). KVBLK=64. S^T = K.Q^T, O^T = V^T.P^T so each
// lane owns one q column end-to-end (in-register softmax, scalar rescale).
// K tile LDS [64][128] swizzle: byte ^= ((row&15)<<4). V^T tile LDS [128][64]
// swizzle: byte ^= ((row&7)<<4). Staged via global_load_lds with pre-swizzled
// global source (m173 pattern).
__global__ __launch_bounds__(256, 2) void flash_attn_k(
    const bf16* __restrict__ Q, const bf16* __restrict__ Kb,
    const bf16* __restrict__ Vt, bf16* __restrict__ O) {
  __shared__ bf16 sh[32768];  // [0,16384): K dbuf; [16384,32768): Vt dbuf
  const int tid = threadIdx.x;
  const int lane = tid & 63;
  const int w = tid >> 6;
  const int h = lane >> 5;
  const int l31 = lane & 31;
  const int bh = blockIdx.y;
  const int b = bh >> 4;
  const int hh = bh & 15;
  const int qb = (gridDim.x - 1 - blockIdx.x) * 128;  // reversed: long blocks first
  const int qw0 = qb + 32 * w;
  const int q = qw0 + l31;

  // Q B-frags: lane holds col q, k = 8h+idx of each 16-wide d slice
  const bf16* qp = Q + (size_t)(b * S_LEN + q) * D_DIM + hh * HD + h * 8;
  bf16x8 qf[8];
#pragma unroll
  for (int ks = 0; ks < 8; ++ks) qf[ks] = *(const bf16x8*)(qp + ks * 16);

  f32x16 ot[4] = {};
  float m_run = -3.0e38f, l_run = 0.f;

  const bf16* Kg = Kb + (size_t)(b * S_LEN) * D_DIM + hh * HD;
  const bf16* Vg = Vt + (size_t)bh * HD * S_LEN;

  // per-lane staging source column offsets (pre-swizzled), in elements
  const int kst_row = 16 * w + (lane >> 4);              // + jj*4
  const int vst_row = 32 * w + (lane >> 3);              // + jj*8
  const int vst_col = (((lane & 7) ^ (lane >> 3)) << 3); // elems
  // per-lane read swizzle bases (bytes)
  const int kxor = (16 * h) ^ ((l31 & 15) << 4);
  const int vxor = (16 * h) ^ ((l31 & 7) << 4);

  const int nt = qb / 64 + 2;
  int cur = 0;

  // prologue stage tile 0
#pragma unroll
  for (int jj = 0; jj < 4; ++jj) {
    int kr = kst_row + jj * 4;
    gload16(Kg + (size_t)kr * D_DIM + ((((lane & 15) ^ (jj * 4 + (lane >> 4)))) << 3),
            &sh[(16 * w + jj * 4) * 128]);
    int vr = vst_row + jj * 8;
    gload16(Vg + (size_t)vr * S_LEN + vst_col,
            &sh[16384 + (32 * w + jj * 8) * 64]);
  }
  __syncthreads();

  for (int t = 0; t < nt; ++t) {
    const int kv0 = t * 64;
    // stage next tile into other buffer
    if (t + 1 < nt) {
      const int nkv = kv0 + 64;
      const int nb = cur ^ 1;
#pragma unroll
      for (int jj = 0; jj < 4; ++jj) {
        int kr = nkv + kst_row + jj * 4;
        gload16(Kg + (size_t)kr * D_DIM + ((((lane & 15) ^ (jj * 4 + (lane >> 4)))) << 3),
                &sh[nb * 8192 + (16 * w + jj * 4) * 128]);
        int vr = vst_row + jj * 8;
        gload16(Vg + (size_t)vr * S_LEN + nkv + vst_col,
                &sh[16384 + nb * 8192 + (32 * w + jj * 8) * 64]);
      }
    }

    if (kv0 <= qw0 + 31) {  // wave-uniform: this tile intersects causal region
      const bf16* Kbuf = &sh[cur * 8192];
      const bf16* Vbuf = &sh[16384 + cur * 8192];

      // S^T = K . Q^T  (rows kv, cols q)
      f32x16 st[2] = {};
#pragma unroll
      for (int g = 0; g < 2; ++g) {
        const bf16* krow = Kbuf + (32 * g + l31) * 128;
#pragma unroll
        for (int ks = 0; ks < 8; ++ks) {
          int cb = ((ks * 32) ^ kxor) >> 1;  // elems
          bf16x8 kf = *(const bf16x8*)(krow + cb);
          st[g] = __builtin_amdgcn_mfma_f32_32x32x16_bf16(kf, qf[ks], st[g], 0, 0, 0);
        }
      }

      // causal mask (only on diagonal-crossing tiles)
      if (kv0 + 63 > qw0) {
#pragma unroll
        for (int g = 0; g < 2; ++g)
#pragma unroll
          for (int r = 0; r < 16; ++r) {
            int kvg = kv0 + 32 * g + (r & 3) + 8 * (r >> 2) + 4 * h;
            if (kvg > q) st[g][r] = -3.0e38f;
          }
      }

      // in-register online softmax (per lane = one q column)
      float mt = -3.0e38f;
#pragma unroll
      for (int g = 0; g < 2; ++g)
#pragma unroll
        for (int r = 0; r < 16; ++r) mt = fmaxf(mt, st[g][r]);
      mt = fmaxf(mt, __shfl_xor(mt, 32));
      float mnew = fmaxf(m_run, mt);
      float alpha = __expf(m_run - mnew);
      float rs = 0.f;
#pragma unroll
      for (int g = 0; g < 2; ++g)
#pragma unroll
        for (int r = 0; r < 16; ++r) {
          float e = __expf(st[g][r] - mnew);
          st[g][r] = e;
          rs += e;
        }
      rs += __shfl_xor(rs, 32);
      if (__any(mt > m_run)) {
#pragma unroll
        for (int n = 0; n < 4; ++n)
#pragma unroll
          for (int r = 0; r < 16; ++r) ot[n][r] *= alpha;
      }
      l_run = l_run * alpha + rs;
      m_run = mnew;

      // pack P to bf16 words: wd[g][j] = (p[2j], p[2j+1])
      unsigned wd[2][8];
#pragma unroll
      for (int g = 0; g < 2; ++g)
#pragma unroll
        for (int j = 0; j < 8; ++j) wd[g][j] = cvtpk(st[g][2 * j], st[g][2 * j + 1]);

      // O^T += V^T . P^T ; per kv slice t4 build B-frag via cross-half swap
#pragma unroll
      for (int t4 = 0; t4 < 4; ++t4) {
        int g = t4 >> 1;
        int a0 = 4 * (t4 & 1) + 2 * h;
        int sidx = 4 * (t4 & 1) + 2 * (1 - h);
        unsigned s0 = (unsigned)__shfl_xor((int)wd[g][sidx], 32);
        unsigned s1 = (unsigned)__shfl_xor((int)wd[g][sidx + 1], 32);
        unsigned pb4[4];
        pb4[0] = h ? s0 : wd[g][a0];
        pb4[1] = h ? s1 : wd[g][a0 + 1];
        pb4[2] = h ? wd[g][a0] : s0;
        pb4[3] = h ? wd[g][a0 + 1] : s1;
        bf16x8 pb = __builtin_bit_cast(bf16x8, *(uint4*)pb4);
#pragma unroll
        for (int n = 0; n < 4; ++n) {
          const bf16* vrow = Vbuf + (32 * n + l31) * 64;
          int cb = ((t4 * 32) ^ vxor) >> 1;
          bf16x8 va = *(const bf16x8*)(vrow + cb);
          ot[n] = __builtin_amdgcn_mfma_f32_32x32x16_bf16(va, pb, ot[n], 0, 0, 0);
        }
      }
    }
    __syncthreads();
    cur ^= 1;
  }

  // epilogue: O^T (lane-owned q column) -> LDS (swizzled) -> coalesced global
  float inv = 1.0f / l_run;
  bf16* ow = &sh[w * 4096];  // 32 rows x 128 cols bf16 per wave
#pragma unroll
  for (int n = 0; n < 4; ++n)
#pragma unroll
    for (int rq = 0; rq < 4; ++rq) {
      int dbase = 32 * n + 8 * rq + 4 * h;
      unsigned u0 = cvtpk(ot[n][4 * rq + 0] * inv, ot[n][4 * rq + 1] * inv);
      unsigned u1 = cvtpk(ot[n][4 * rq + 2] * inv, ot[n][4 * rq + 3] * inv);
      uint2 uu = make_uint2(u0, u1);
      *(uint2*)(ow + l31 * 128 + (dbase ^ ((l31 & 15) << 3))) = uu;
    }
  __syncthreads();
#pragma unroll
  for (int p = 0; p < 8; ++p) {
    int qr = p * 4 + (lane >> 4);
    int ce = ((((lane & 15) << 4) ^ ((qr & 15) << 4)) >> 1);
    bf16x8 vrow = *(const bf16x8*)(ow + qr * 128 + ce);
    *(bf16x8*)(O + (size_t)(b * S_LEN + qw0 + qr) * D_DIM + hh * HD + (lane & 15) * 8) = vrow;
  }
}

// ---------------- launch ----------------

extern "C" void kernel_launch(void* const* d_in, const int* in_sizes, int n_in,
                              void* d_out, int out_size, void* d_ws, size_t ws_size,
                              hipStream_t stream) {
  (void)in_sizes; (void)n_in; (void)out_size; (void)ws_size;
  const float* x  = (const float*)d_in[0];
  const float* wq = (const float*)d_in[1];
  const float* wk = (const float*)d_in[2];
  const float* wv = (const float*)d_in[3];
  const float* wo = (const float*)d_in[4];
  float* out = (float*)d_out;

  char* ws = (char*)d_ws;
  const size_t MB = 1u << 20;
  bf16* xb  = (bf16*)(ws + 0 * MB);
  bf16* Ob  = xb;
  bf16* wTq = (bf16*)(ws + 16 * MB);
  bf16* wTk = (bf16*)(ws + 24 * MB);
  bf16* wTv = (bf16*)(ws + 32 * MB);
  bf16* wTo = (bf16*)(ws + 40 * MB);
  bf16* Qb  = (bf16*)(ws + 48 * MB);
  bf16* Kb  = (bf16*)(ws + 64 * MB);
  bf16* Vb  = (bf16*)(ws + 80 * MB);
  bf16* Vtb = (bf16*)(ws + 96 * MB);
  float2* tab = (float2*)(ws + 112 * MB);

  rope_table_k<<<512, 256, 0, stream>>>(tab);
  convert_x_k<<<8192, 256, 0, stream>>>(x, xb);
  dim3 tg(32, 32);
  transpose_w_k<<<tg, 256, 0, stream>>>(wq, wTq);
  transpose_w_k<<<tg, 256, 0, stream>>>(wk, wTk);
  transpose_w_k<<<tg, 256, 0, stream>>>(wv, wTv);
  transpose_w_k<<<tg, 256, 0, stream>>>(wo, wTo);

  dim3 gg(D_DIM / 128, NROW / 128);
  gemm_bt_k<bf16><<<gg, 256, 0, stream>>>(xb, wTq, Qb, NROW, D_DIM, D_DIM);
  gemm_bt_k<bf16><<<gg, 256, 0, stream>>>(xb, wTk, Kb, NROW, D_DIM, D_DIM);
  gemm_bt_k<bf16><<<gg, 256, 0, stream>>>(xb, wTv, Vb, NROW, D_DIM, D_DIM);

  rope_apply_k<<<16384, 256, 0, stream>>>(Qb, Kb, tab);
  transpose_v_k<<<dim3(32, 2, 32), 256, 0, stream>>>(Vb, Vtb);

  flash_attn_k<<<dim3(S_LEN / 128, NB * NH), 256, 0, stream>>>(Qb, Kb, Vtb, Ob);

  gemm_bt_k<float><<<gg, 256, 0, stream>>>(Ob, wTo, out, NROW, D_DIM, D_DIM);
}

// Round 3
// 388.553 us; speedup vs baseline: 1.9709x; 1.0663x over previous
//
#include <hip/hip_runtime.h>

#define S_LEN 2048
#define D_DIM 2048
#define NH 16
#define HD 128
#define NB 2
#define NROW (NB * S_LEN)  // 4096
#define QKV_STR 6144       // fused Q|K|V row stride

typedef unsigned short bf16;
typedef __attribute__((ext_vector_type(8))) short bf16x8;
typedef __attribute__((ext_vector_type(4))) float f32x4;
typedef __attribute__((ext_vector_type(16))) float f32x16;
typedef __attribute__((address_space(3))) unsigned int as3u;
typedef __attribute__((address_space(1))) unsigned int as1u;

__device__ __forceinline__ void gload16(const void* g, void* l) {
  __builtin_amdgcn_global_load_lds((const as1u*)g, (as3u*)l, 16, 0, 0);
}

__device__ __forceinline__ unsigned short f2bf(float f) {
  unsigned u = __builtin_bit_cast(unsigned, f);
  u += 0x7FFFu + ((u >> 16) & 1u);
  return (unsigned short)(u >> 16);
}
__device__ __forceinline__ float bf2f(unsigned short b) {
  return __builtin_bit_cast(float, (unsigned)b << 16);
}
__device__ __forceinline__ unsigned cvtpk(float lo, float hi) {
  unsigned r;
  asm("v_cvt_pk_bf16_f32 %0, %1, %2" : "=v"(r) : "v"(lo), "v"(hi));
  return r;
}
__device__ __forceinline__ float exp2a(float x) {  // 2^x
  float r;
  asm("v_exp_f32 %0, %1" : "=v"(r) : "v"(x));
  return r;
}

// ---------------- small prep kernels ----------------

__global__ void rope_table_k(float2* __restrict__ tab) {
  int i = blockIdx.x * 256 + threadIdx.x;  // S*64
  int s = i >> 6, d = i & 63;
  float invf = powf(10000.0f, -(float)d * (1.0f / 64.0f));
  float ang = (float)s * invf;
  tab[i] = make_float2(cosf(ang), sinf(ang));
}

__global__ void convert_x_k(const float* __restrict__ src, bf16* __restrict__ dst) {
  int i = (blockIdx.x * 256 + threadIdx.x) * 4;
  float4 v = *(const float4*)(src + i);
  ushort4 w;
  w.x = f2bf(v.x); w.y = f2bf(v.y); w.z = f2bf(v.z); w.w = f2bf(v.w);
  *(ushort4*)(dst + i) = w;
}

__global__ void transpose_w_k(const float* __restrict__ W, bf16* __restrict__ Wt) {
  __shared__ float t[64][65];
  int c0 = blockIdx.x * 64, r0 = blockIdx.y * 64;
  int tx = threadIdx.x & 63, ty = threadIdx.x >> 6;
#pragma unroll
  for (int i = 0; i < 16; ++i)
    t[ty + i * 4][tx] = W[(size_t)(r0 + ty + i * 4) * D_DIM + c0 + tx];
  __syncthreads();
#pragma unroll
  for (int i = 0; i < 16; ++i)
    Wt[(size_t)(c0 + ty + i * 4) * D_DIM + r0 + tx] = f2bf(t[tx][ty + i * 4]);
}

// V slice of QKV [row][4096+*] -> Vt [bh][d][s]
__global__ void transpose_v_k(const bf16* __restrict__ Vsrc, bf16* __restrict__ Vt) {
  __shared__ bf16 t[64][65];
  int bh = blockIdx.z;
  int b = bh >> 4, h = bh & 15;
  int s0 = blockIdx.x * 64, d0 = blockIdx.y * 64;
  int tx = threadIdx.x & 63, ty = threadIdx.x >> 6;
  const bf16* src = Vsrc + (size_t)(b * S_LEN + s0) * QKV_STR + h * HD + d0;
#pragma unroll
  for (int i = 0; i < 16; ++i)
    t[ty + i * 4][tx] = src[(size_t)(ty + i * 4) * QKV_STR + tx];
  __syncthreads();
  bf16* dst = Vt + ((size_t)bh * HD + d0) * S_LEN + s0;
#pragma unroll
  for (int i = 0; i < 16; ++i)
    dst[(size_t)(ty + i * 4) * S_LEN + tx] = t[tx][ty + i * 4];
}

// RoPE in-place on fused QKV; scale*log2e folded into Q (softmax in log2 domain).
__global__ void rope_apply_k(bf16* __restrict__ qkv, const float2* __restrict__ tab) {
  int i = blockIdx.x * 256 + threadIdx.x;  // NROW*NH*64
  int d = i & 63;
  int t = i >> 6;
  int h = t & 15;
  int row = t >> 4;
  int s = row & (S_LEN - 1);
  const float qscale = 0.12751743f;  // 128^-0.5 * log2(e)
  float2 cs = tab[s * 64 + d];
  size_t base = (size_t)row * QKV_STR + h * HD + d;
  float x1 = bf2f(qkv[base]), x2 = bf2f(qkv[base + 64]);
  qkv[base]      = f2bf((x1 * cs.x - x2 * cs.y) * qscale);
  qkv[base + 64] = f2bf((x2 * cs.x + x1 * cs.y) * qscale);
  size_t kb2 = base + 2048;
  float y1 = bf2f(qkv[kb2]), y2 = bf2f(qkv[kb2 + 64]);
  qkv[kb2]      = f2bf(y1 * cs.x - y2 * cs.y);
  qkv[kb2 + 64] = f2bf(y2 * cs.x + y1 * cs.y);
}

// ---------------- GEMM: C[M][N] = A[M][K] @ Bt[N][K]^T ----------------

__device__ __forceinline__ void storec(bf16* p, float v) { *p = f2bf(v); }
__device__ __forceinline__ void storec(float* p, float v) { *p = v; }

template <typename OutT>
__global__ __launch_bounds__(256) void gemm_bt_k(
    const bf16* __restrict__ A, const bf16* __restrict__ Bt,
    OutT* __restrict__ C, int M, int N, int K) {
  __shared__ bf16 As[128 * 32];
  __shared__ bf16 Bs[128 * 32];
  const int tid = threadIdx.x;
  const int lane = tid & 63;
  const int wid = tid >> 6;
  const int bm = blockIdx.y * 128;
  const int bn = blockIdx.x * 128;
  const int wr = (wid >> 1) * 64;
  const int wc = (wid & 1) * 64;
  const int lr = lane & 15;
  const int kg = lane >> 4;

  f32x4 acc[4][4] = {};

  const int c0 = wid * 2;
  const int srow = lane >> 2;
  const int scol = (lane & 3) * 8;
  const bf16* Ap0 = A + (size_t)(bm + c0 * 16 + srow) * K + scol;
  const bf16* Ap1 = Ap0 + (size_t)16 * K;
  const bf16* Bp0 = Bt + (size_t)(bn + c0 * 16 + srow) * K + scol;
  const bf16* Bp1 = Bp0 + (size_t)16 * K;
  bf16* Asd0 = &As[c0 * 512];
  bf16* Asd1 = &As[(c0 + 1) * 512];
  bf16* Bsd0 = &Bs[c0 * 512];
  bf16* Bsd1 = &Bs[(c0 + 1) * 512];

  for (int k0 = 0; k0 < K; k0 += 32) {
    __syncthreads();
    gload16(Ap0 + k0, Asd0);
    gload16(Ap1 + k0, Asd1);
    gload16(Bp0 + k0, Bsd0);
    gload16(Bp1 + k0, Bsd1);
    __syncthreads();
    bf16x8 a[4], b[4];
#pragma unroll
    for (int m = 0; m < 4; ++m)
      a[m] = *(const bf16x8*)&As[(wr + m * 16 + lr) * 32 + kg * 8];
#pragma unroll
    for (int n = 0; n < 4; ++n)
      b[n] = *(const bf16x8*)&Bs[(wc + n * 16 + lr) * 32 + kg * 8];
#pragma unroll
    for (int m = 0; m < 4; ++m)
#pragma unroll
      for (int n = 0; n < 4; ++n)
        acc[m][n] = __builtin_amdgcn_mfma_f32_16x16x32_bf16(a[m], b[n], acc[m][n], 0, 0, 0);
  }

#pragma unroll
  for (int m = 0; m < 4; ++m) {
    int row0 = bm + wr + m * 16 + kg * 4;
#pragma unroll
    for (int n = 0; n < 4; ++n) {
      int col = bn + wc + n * 16 + lr;
#pragma unroll
      for (int r = 0; r < 4; ++r)
        storec(&C[(size_t)(row0 + r) * N + col], acc[m][n][r]);
    }
  }
}

// ---------------- causal flash attention, 32x32 swapped layout ----------------
// 48KB LDS: K double-buffered (2x16KB), V single-buffered (16KB) -> 3 blocks/CU.
// Raw s_barrier + counted vmcnt: K(t+1) issued at top of iter, V(t+1) after the
// post-PV barrier; vmcnt(8) gates QK(t), vmcnt(4) gates PV(t). Softmax in log2
// domain (scale*log2e folded into Q), tree max/sum, defer-max THR=8.
__global__ __launch_bounds__(256, 3) void flash_attn_k(
    const bf16* __restrict__ Q, const bf16* __restrict__ Kb,
    const bf16* __restrict__ Vt, bf16* __restrict__ O) {
  __shared__ bf16 sh[24576];  // elems: K0 @0, K1 @8192, V @16384
  const int tid = threadIdx.x;
  const int lane = tid & 63;
  const int w = tid >> 6;
  const int h = lane >> 5;
  const int l31 = lane & 31;
  const int bh = blockIdx.y;
  const int b = bh >> 4;
  const int hh = bh & 15;
  const int qb = (gridDim.x - 1 - blockIdx.x) * 128;  // long blocks first
  const int qw0 = qb + 32 * w;
  const int q = qw0 + l31;

  const bf16* qp = Q + (size_t)(b * S_LEN + q) * QKV_STR + hh * HD + h * 8;
  bf16x8 qf[8];
#pragma unroll
  for (int ks = 0; ks < 8; ++ks) qf[ks] = *(const bf16x8*)(qp + ks * 16);

  f32x16 ot[4] = {};
  float m_run = -3.0e38f, l_run = 0.f;

  const bf16* Kg = Kb + (size_t)(b * S_LEN) * QKV_STR + hh * HD;
  const bf16* Vg = Vt + (size_t)bh * HD * S_LEN;

  const int kst_row = 16 * w + (lane >> 4);
  const int vst_row = 32 * w + (lane >> 3);
  const int vst_col = (((lane & 7) ^ (lane >> 3)) << 3);
  const int kxor = (16 * h) ^ ((l31 & 15) << 4);
  const int vxor = (16 * h) ^ ((l31 & 7) << 4);

  auto stageK = [&](int kv0, int buf) {
#pragma unroll
    for (int jj = 0; jj < 4; ++jj) {
      int kr = (kv0 + kst_row + jj * 4) & (S_LEN - 1);
      gload16(Kg + (size_t)kr * QKV_STR + (((lane & 15) ^ (jj * 4 + (lane >> 4))) << 3),
              &sh[buf * 8192 + (16 * w + jj * 4) * 128]);
    }
  };
  auto stageV = [&](int kv0) {
    int c = (kv0 & (S_LEN - 1)) + vst_col;
#pragma unroll
    for (int jj = 0; jj < 4; ++jj) {
      int vr = vst_row + jj * 8;
      gload16(Vg + (size_t)vr * S_LEN + c, &sh[16384 + (32 * w + jj * 8) * 64]);
    }
  };

  stageK(0, 0);
  stageV(0);

  const int nt = qb / 64 + 2;
  for (int t = 0; t < nt; ++t) {
    const int kv0 = t * 64;
    __builtin_amdgcn_s_barrier();
    stageK(kv0 + 64, (t + 1) & 1);

    if (kv0 <= qw0 + 31) {
      asm volatile("s_waitcnt vmcnt(8)" ::: "memory");
      __builtin_amdgcn_sched_barrier(0);
      const bf16* Kbuf = &sh[(t & 1) * 8192];
      const bf16* krow0 = Kbuf + (size_t)l31 * 128;
      const bf16* krow1 = krow0 + 32 * 128;

      f32x16 st0 = {}, st1 = {};
#pragma unroll
      for (int ks = 0; ks < 8; ++ks) {
        int cb = ((ks * 32) ^ kxor) >> 1;
        bf16x8 kf0 = *(const bf16x8*)(krow0 + cb);
        bf16x8 kf1 = *(const bf16x8*)(krow1 + cb);
        st0 = __builtin_amdgcn_mfma_f32_32x32x16_bf16(kf0, qf[ks], st0, 0, 0, 0);
        st1 = __builtin_amdgcn_mfma_f32_32x32x16_bf16(kf1, qf[ks], st1, 0, 0, 0);
      }

      if (kv0 + 63 > qw0) {
#pragma unroll
        for (int r = 0; r < 16; ++r) {
          int kvg = kv0 + (r & 3) + 8 * (r >> 2) + 4 * h;
          if (kvg > q) st0[r] = -3.0e38f;
          if (kvg + 32 > q) st1[r] = -3.0e38f;
        }
      }

      // tree max over 32 lane-local values + cross-half
      float tm[8];
#pragma unroll
      for (int r = 0; r < 8; ++r)
        tm[r] = fmaxf(fmaxf(st0[r], st0[r + 8]), fmaxf(st1[r], st1[r + 8]));
#pragma unroll
      for (int r = 0; r < 4; ++r) tm[r] = fmaxf(tm[r], tm[r + 4]);
      float mt = fmaxf(fmaxf(tm[0], tm[1]), fmaxf(tm[2], tm[3]));
      mt = fmaxf(mt, __shfl_xor(mt, 32));

      if (__any(mt > m_run + 8.0f)) {  // defer-max: rescale only on real growth
        float mnew = fmaxf(m_run, mt);
        float alpha = exp2a(m_run - mnew);
        l_run *= alpha;
#pragma unroll
        for (int n = 0; n < 4; ++n)
#pragma unroll
          for (int r = 0; r < 16; ++r) ot[n][r] *= alpha;
        m_run = mnew;
      }

      float rs[16];
#pragma unroll
      for (int r = 0; r < 16; ++r) {
        st0[r] = exp2a(st0[r] - m_run);
        st1[r] = exp2a(st1[r] - m_run);
        rs[r] = st0[r] + st1[r];
      }
#pragma unroll
      for (int r = 0; r < 8; ++r) rs[r] += rs[r + 8];
#pragma unroll
      for (int r = 0; r < 4; ++r) rs[r] += rs[r + 4];
      float rsum = (rs[0] + rs[1]) + (rs[2] + rs[3]);
      rsum += __shfl_xor(rsum, 32);
      l_run += rsum;

      // pack P to bf16 pairs
      unsigned wd0[8], wd1[8];
#pragma unroll
      for (int j = 0; j < 8; ++j) {
        wd0[j] = cvtpk(st0[2 * j], st0[2 * j + 1]);
        wd1[j] = cvtpk(st1[2 * j], st1[2 * j + 1]);
      }

      asm volatile("s_waitcnt vmcnt(4)" ::: "memory");
      __builtin_amdgcn_sched_barrier(0);
      const bf16* Vbuf = &sh[16384];
#pragma unroll
      for (int t4 = 0; t4 < 4; ++t4) {
        const unsigned* wd = (t4 >> 1) ? wd1 : wd0;
        int a0 = 4 * (t4 & 1) + 2 * h;
        int sidx = 4 * (t4 & 1) + 2 * (1 - h);
        unsigned s0 = (unsigned)__shfl_xor((int)wd[sidx], 32);
        unsigned s1 = (unsigned)__shfl_xor((int)wd[sidx + 1], 32);
        unsigned pb4[4];
        pb4[0] = h ? s0 : wd[a0];
        pb4[1] = h ? s1 : wd[a0 + 1];
        pb4[2] = h ? wd[a0] : s0;
        pb4[3] = h ? wd[a0 + 1] : s1;
        bf16x8 pb = __builtin_bit_cast(bf16x8, *(uint4*)pb4);
        int cb = ((t4 * 32) ^ vxor) >> 1;
#pragma unroll
        for (int n = 0; n < 4; ++n) {
          bf16x8 va = *(const bf16x8*)(Vbuf + (size_t)(32 * n + l31) * 64 + cb);
          ot[n] = __builtin_amdgcn_mfma_f32_32x32x16_bf16(va, pb, ot[n], 0, 0, 0);
        }
      }
    }

    __builtin_amdgcn_s_barrier();
    stageV(kv0 + 64);
  }

  asm volatile("s_waitcnt vmcnt(0)" ::: "memory");
  __builtin_amdgcn_s_barrier();

  // epilogue: O^T -> LDS (swizzled) -> coalesced global
  float inv = 1.0f / l_run;
  bf16* ow = &sh[w * 4096];  // 32 rows x 128 cols per wave
#pragma unroll
  for (int n = 0; n < 4; ++n)
#pragma unroll
    for (int rq = 0; rq < 4; ++rq) {
      int dbase = 32 * n + 8 * rq + 4 * h;
      unsigned u0 = cvtpk(ot[n][4 * rq + 0] * inv, ot[n][4 * rq + 1] * inv);
      unsigned u1 = cvtpk(ot[n][4 * rq + 2] * inv, ot[n][4 * rq + 3] * inv);
      uint2 uu = make_uint2(u0, u1);
      *(uint2*)(ow + l31 * 128 + (dbase ^ ((l31 & 15) << 3))) = uu;
    }
  __syncthreads();
#pragma unroll
  for (int p = 0; p < 8; ++p) {
    int qr = p * 4 + (lane >> 4);
    int ce = ((((lane & 15) << 4) ^ ((qr & 15) << 4)) >> 1);
    bf16x8 vrow = *(const bf16x8*)(ow + qr * 128 + ce);
    *(bf16x8*)(O + (size_t)(b * S_LEN + qw0 + qr) * D_DIM + hh * HD + (lane & 15) * 8) = vrow;
  }
}

// ---------------- launch ----------------

extern "C" void kernel_launch(void* const* d_in, const int* in_sizes, int n_in,
                              void* d_out, int out_size, void* d_ws, size_t ws_size,
                              hipStream_t stream) {
  (void)in_sizes; (void)n_in; (void)out_size; (void)ws_size;
  const float* x  = (const float*)d_in[0];
  const float* wq = (const float*)d_in[1];
  const float* wk = (const float*)d_in[2];
  const float* wv = (const float*)d_in[3];
  const float* wo = (const float*)d_in[4];
  float* out = (float*)d_out;

  char* ws = (char*)d_ws;
  const size_t MB = 1u << 20;
  bf16* xb    = (bf16*)(ws + 0 * MB);    // 16MB; reused as O after attention
  bf16* Ob    = xb;
  bf16* wTall = (bf16*)(ws + 16 * MB);   // 24MB: wq^T | wk^T | wv^T rows
  bf16* wTo   = (bf16*)(ws + 40 * MB);   // 8MB
  bf16* QKV   = (bf16*)(ws + 48 * MB);   // 48MB: [4096][6144]
  bf16* Vtb   = (bf16*)(ws + 96 * MB);   // 16MB
  float2* tab = (float2*)(ws + 112 * MB);

  rope_table_k<<<512, 256, 0, stream>>>(tab);
  convert_x_k<<<8192, 256, 0, stream>>>(x, xb);
  dim3 tg(32, 32);
  transpose_w_k<<<tg, 256, 0, stream>>>(wq, wTall);
  transpose_w_k<<<tg, 256, 0, stream>>>(wk, wTall + (size_t)2048 * D_DIM);
  transpose_w_k<<<tg, 256, 0, stream>>>(wv, wTall + (size_t)4096 * D_DIM);
  transpose_w_k<<<tg, 256, 0, stream>>>(wo, wTo);

  // fused QKV projection: [4096][2048] @ [6144][2048]^T -> [4096][6144]
  gemm_bt_k<bf16><<<dim3(QKV_STR / 128, NROW / 128), 256, 0, stream>>>(
      xb, wTall, QKV, NROW, QKV_STR, D_DIM);

  rope_apply_k<<<16384, 256, 0, stream>>>(QKV, tab);
  transpose_v_k<<<dim3(32, 2, 32), 256, 0, stream>>>(QKV + 4096, Vtb);

  flash_attn_k<<<dim3(S_LEN / 128, NB * NH), 256, 0, stream>>>(
      QKV, QKV + 2048, Vtb, Ob);

  gemm_bt_k<float><<<dim3(D_DIM / 128, NROW / 128), 256, 0, stream>>>(
      Ob, wTo, out, NROW, D_DIM, D_DIM);
}

// Round 4
// 349.905 us; speedup vs baseline: 2.1886x; 1.1105x over previous
//
#include <hip/hip_runtime.h>

#define S_LEN 2048
#define D_DIM 2048
#define NH 16
#define HD 128
#define NB 2
#define NROW (NB * S_LEN)  // 4096
#define QKV_STR 6144       // fused Q|K|V row stride

typedef unsigned short bf16;
typedef __attribute__((ext_vector_type(8))) short bf16x8;
typedef __attribute__((ext_vector_type(4))) float f32x4;
typedef __attribute__((ext_vector_type(16))) float f32x16;
typedef __attribute__((address_space(3))) unsigned int as3u;
typedef __attribute__((address_space(1))) unsigned int as1u;

__device__ __forceinline__ void gload16(const void* g, void* l) {
  __builtin_amdgcn_global_load_lds((const as1u*)g, (as3u*)l, 16, 0, 0);
}

__device__ __forceinline__ unsigned short f2bf(float f) {
  unsigned u = __builtin_bit_cast(unsigned, f);
  u += 0x7FFFu + ((u >> 16) & 1u);
  return (unsigned short)(u >> 16);
}
__device__ __forceinline__ float bf2f(unsigned short b) {
  return __builtin_bit_cast(float, (unsigned)b << 16);
}
__device__ __forceinline__ unsigned cvtpk(float lo, float hi) {
  unsigned r;
  asm("v_cvt_pk_bf16_f32 %0, %1, %2" : "=v"(r) : "v"(lo), "v"(hi));
  return r;
}
__device__ __forceinline__ float exp2a(float x) {  // 2^x
  float r;
  asm("v_exp_f32 %0, %1" : "=v"(r) : "v"(x));
  return r;
}

// ---------------- small prep kernels ----------------

__global__ void rope_table_k(float2* __restrict__ tab) {
  int i = blockIdx.x * 256 + threadIdx.x;  // S*64
  int s = i >> 6, d = i & 63;
  float invf = powf(10000.0f, -(float)d * (1.0f / 64.0f));
  float ang = (float)s * invf;
  tab[i] = make_float2(cosf(ang), sinf(ang));
}

__global__ void convert_x_k(const float* __restrict__ src, bf16* __restrict__ dst) {
  int i = (blockIdx.x * 256 + threadIdx.x) * 4;
  float4 v = *(const float4*)(src + i);
  ushort4 w;
  w.x = f2bf(v.x); w.y = f2bf(v.y); w.z = f2bf(v.z); w.w = f2bf(v.w);
  *(ushort4*)(dst + i) = w;
}

__global__ void transpose_w_k(const float* __restrict__ W, bf16* __restrict__ Wt) {
  __shared__ float t[64][65];
  int c0 = blockIdx.x * 64, r0 = blockIdx.y * 64;
  int tx = threadIdx.x & 63, ty = threadIdx.x >> 6;
#pragma unroll
  for (int i = 0; i < 16; ++i)
    t[ty + i * 4][tx] = W[(size_t)(r0 + ty + i * 4) * D_DIM + c0 + tx];
  __syncthreads();
#pragma unroll
  for (int i = 0; i < 16; ++i)
    Wt[(size_t)(c0 + ty + i * 4) * D_DIM + r0 + tx] = f2bf(t[tx][ty + i * 4]);
}

// V slice of QKV [row][4096+*] -> Vt [bh][d][s]
__global__ void transpose_v_k(const bf16* __restrict__ Vsrc, bf16* __restrict__ Vt) {
  __shared__ bf16 t[64][65];
  int bh = blockIdx.z;
  int b = bh >> 4, h = bh & 15;
  int s0 = blockIdx.x * 64, d0 = blockIdx.y * 64;
  int tx = threadIdx.x & 63, ty = threadIdx.x >> 6;
  const bf16* src = Vsrc + (size_t)(b * S_LEN + s0) * QKV_STR + h * HD + d0;
#pragma unroll
  for (int i = 0; i < 16; ++i)
    t[ty + i * 4][tx] = src[(size_t)(ty + i * 4) * QKV_STR + tx];
  __syncthreads();
  bf16* dst = Vt + ((size_t)bh * HD + d0) * S_LEN + s0;
#pragma unroll
  for (int i = 0; i < 16; ++i)
    dst[(size_t)(ty + i * 4) * S_LEN + tx] = t[tx][ty + i * 4];
}

// RoPE in-place on fused QKV; scale*log2e folded into Q (softmax in log2 domain).
__global__ void rope_apply_k(bf16* __restrict__ qkv, const float2* __restrict__ tab) {
  int i = blockIdx.x * 256 + threadIdx.x;  // NROW*NH*64
  int d = i & 63;
  int t = i >> 6;
  int h = t & 15;
  int row = t >> 4;
  int s = row & (S_LEN - 1);
  const float qscale = 0.12751743f;  // 128^-0.5 * log2(e)
  float2 cs = tab[s * 64 + d];
  size_t base = (size_t)row * QKV_STR + h * HD + d;
  float x1 = bf2f(qkv[base]), x2 = bf2f(qkv[base + 64]);
  qkv[base]      = f2bf((x1 * cs.x - x2 * cs.y) * qscale);
  qkv[base + 64] = f2bf((x2 * cs.x + x1 * cs.y) * qscale);
  size_t kb2 = base + 2048;
  float y1 = bf2f(qkv[kb2]), y2 = bf2f(qkv[kb2 + 64]);
  qkv[kb2]      = f2bf(y1 * cs.x - y2 * cs.y);
  qkv[kb2 + 64] = f2bf(y2 * cs.x + y1 * cs.y);
}

// ---------------- GEMM: C[M][N] = A[M][K] @ Bt[N][K]^T ----------------

__device__ __forceinline__ void storec(bf16* p, float v) { *p = f2bf(v); }
__device__ __forceinline__ void storec(float* p, float v) { *p = v; }

template <typename OutT>
__global__ __launch_bounds__(256) void gemm_bt_k(
    const bf16* __restrict__ A, const bf16* __restrict__ Bt,
    OutT* __restrict__ C, int M, int N, int K) {
  __shared__ bf16 As[128 * 32];
  __shared__ bf16 Bs[128 * 32];
  const int tid = threadIdx.x;
  const int lane = tid & 63;
  const int wid = tid >> 6;
  const int bm = blockIdx.y * 128;
  const int bn = blockIdx.x * 128;
  const int wr = (wid >> 1) * 64;
  const int wc = (wid & 1) * 64;
  const int lr = lane & 15;
  const int kg = lane >> 4;

  f32x4 acc[4][4] = {};

  const int c0 = wid * 2;
  const int srow = lane >> 2;
  const int scol = (lane & 3) * 8;
  const bf16* Ap0 = A + (size_t)(bm + c0 * 16 + srow) * K + scol;
  const bf16* Ap1 = Ap0 + (size_t)16 * K;
  const bf16* Bp0 = Bt + (size_t)(bn + c0 * 16 + srow) * K + scol;
  const bf16* Bp1 = Bp0 + (size_t)16 * K;
  bf16* Asd0 = &As[c0 * 512];
  bf16* Asd1 = &As[(c0 + 1) * 512];
  bf16* Bsd0 = &Bs[c0 * 512];
  bf16* Bsd1 = &Bs[(c0 + 1) * 512];

  for (int k0 = 0; k0 < K; k0 += 32) {
    __syncthreads();
    gload16(Ap0 + k0, Asd0);
    gload16(Ap1 + k0, Asd1);
    gload16(Bp0 + k0, Bsd0);
    gload16(Bp1 + k0, Bsd1);
    __syncthreads();
    bf16x8 a[4], b[4];
#pragma unroll
    for (int m = 0; m < 4; ++m)
      a[m] = *(const bf16x8*)&As[(wr + m * 16 + lr) * 32 + kg * 8];
#pragma unroll
    for (int n = 0; n < 4; ++n)
      b[n] = *(const bf16x8*)&Bs[(wc + n * 16 + lr) * 32 + kg * 8];
#pragma unroll
    for (int m = 0; m < 4; ++m)
#pragma unroll
      for (int n = 0; n < 4; ++n)
        acc[m][n] = __builtin_amdgcn_mfma_f32_16x16x32_bf16(a[m], b[n], acc[m][n], 0, 0, 0);
  }

#pragma unroll
  for (int m = 0; m < 4; ++m) {
    int row0 = bm + wr + m * 16 + kg * 4;
#pragma unroll
    for (int n = 0; n < 4; ++n) {
      int col = bn + wc + n * 16 + lr;
#pragma unroll
      for (int r = 0; r < 4; ++r)
        storec(&C[(size_t)(row0 + r) * N + col], acc[m][n][r]);
    }
  }
}

// ---------------- causal flash attention, 32x32 swapped, T15 pipelined -------
// 64KB LDS: K dbuf (2x16KB) + V dbuf (2x16KB). Schedule per iter t:
//   A: stage V(t+1), K(t+2)                      (gload_lds, 8 loads)
//   B: QK(t+1) MFMAs (ping-pong S-state)  ||  softmax(t) VALU on prev state
//   C: PV(t) MFMAs
//   D: vmcnt(0) drain -> s_barrier  (wait-THEN-barrier: cross-wave safe)
// K is staged 2 tiles ahead so QK(t+1) can run during iter t (T15 overlap).
#define FBODY(T, CUR0, CUR1, NXT0, NXT1)                                         \
  {                                                                              \
    const int kv0_ = (T) * 64;                                                   \
    stageV(kv0_ + 64, ((T) + 1) & 1);                                            \
    stageK(kv0_ + 128, (T) & 1);                                                 \
    if (kv0_ + 64 <= qw0 + 31) {                                                 \
      NXT0 = 0.0f; NXT1 = 0.0f;                                                  \
      const bf16* krow0_ = &sh[(((T) + 1) & 1) * 8192] + (size_t)l31 * 128;      \
      const bf16* krow1_ = krow0_ + 32 * 128;                                    \
      _Pragma("unroll")                                                          \
      for (int ks = 0; ks < 8; ++ks) {                                           \
        int cb_ = ((ks * 32) ^ kxor) >> 1;                                       \
        bf16x8 kf0_ = *(const bf16x8*)(krow0_ + cb_);                            \
        bf16x8 kf1_ = *(const bf16x8*)(krow1_ + cb_);                            \
        NXT0 = __builtin_amdgcn_mfma_f32_32x32x16_bf16(kf0_, qf[ks], NXT0, 0, 0, 0); \
        NXT1 = __builtin_amdgcn_mfma_f32_32x32x16_bf16(kf1_, qf[ks], NXT1, 0, 0, 0); \
      }                                                                          \
    }                                                                            \
    if (kv0_ <= qw0 + 31) {                                                      \
      if (kv0_ + 63 > qw0) {                                                     \
        _Pragma("unroll")                                                        \
        for (int r = 0; r < 16; ++r) {                                           \
          int kvg_ = kv0_ + (r & 3) + 8 * (r >> 2) + 4 * h;                      \
          if (kvg_ > q) CUR0[r] = -3.0e38f;                                      \
          if (kvg_ + 32 > q) CUR1[r] = -3.0e38f;                                 \
        }                                                                        \
      }                                                                          \
      float tm_[8];                                                              \
      _Pragma("unroll")                                                          \
      for (int r = 0; r < 8; ++r)                                                \
        tm_[r] = fmaxf(fmaxf(CUR0[r], CUR0[r + 8]), fmaxf(CUR1[r], CUR1[r + 8])); \
      _Pragma("unroll")                                                          \
      for (int r = 0; r < 4; ++r) tm_[r] = fmaxf(tm_[r], tm_[r + 4]);            \
      float mt_ = fmaxf(fmaxf(tm_[0], tm_[1]), fmaxf(tm_[2], tm_[3]));           \
      mt_ = fmaxf(mt_, __shfl_xor(mt_, 32));                                     \
      if (__any(mt_ > m_run + 8.0f)) {                                           \
        float mnew_ = fmaxf(m_run, mt_);                                         \
        float alpha_ = exp2a(m_run - mnew_);                                     \
        l_run *= alpha_;                                                         \
        _Pragma("unroll")                                                        \
        for (int n = 0; n < 4; ++n)                                              \
          _Pragma("unroll")                                                      \
          for (int r = 0; r < 16; ++r) ot[n][r] *= alpha_;                       \
        m_run = mnew_;                                                           \
      }                                                                          \
      float rs_[16];                                                             \
      _Pragma("unroll")                                                          \
      for (int r = 0; r < 16; ++r) {                                             \
        CUR0[r] = exp2a(CUR0[r] - m_run);                                        \
        CUR1[r] = exp2a(CUR1[r] - m_run);                                        \
        rs_[r] = CUR0[r] + CUR1[r];                                              \
      }                                                                          \
      _Pragma("unroll")                                                          \
      for (int r = 0; r < 8; ++r) rs_[r] += rs_[r + 8];                          \
      _Pragma("unroll")                                                          \
      for (int r = 0; r < 4; ++r) rs_[r] += rs_[r + 4];                          \
      float rsum_ = (rs_[0] + rs_[1]) + (rs_[2] + rs_[3]);                       \
      rsum_ += __shfl_xor(rsum_, 32);                                            \
      l_run += rsum_;                                                            \
      unsigned wd0_[8], wd1_[8];                                                 \
      _Pragma("unroll")                                                          \
      for (int j = 0; j < 8; ++j) {                                              \
        wd0_[j] = cvtpk(CUR0[2 * j], CUR0[2 * j + 1]);                           \
        wd1_[j] = cvtpk(CUR1[2 * j], CUR1[2 * j + 1]);                           \
      }                                                                          \
      const bf16* Vbuf_ = &sh[16384 + ((T) & 1) * 8192];                         \
      _Pragma("unroll")                                                          \
      for (int t4 = 0; t4 < 4; ++t4) {                                           \
        const unsigned* wdp_ = (t4 >> 1) ? wd1_ : wd0_;                          \
        int a0_ = 4 * (t4 & 1) + 2 * h;                                          \
        int sidx_ = 4 * (t4 & 1) + 2 * (1 - h);                                  \
        unsigned s0_ = (unsigned)__shfl_xor((int)wdp_[sidx_], 32);               \
        unsigned s1_ = (unsigned)__shfl_xor((int)wdp_[sidx_ + 1], 32);           \
        unsigned pb4_[4];                                                        \
        pb4_[0] = h ? s0_ : wdp_[a0_];                                           \
        pb4_[1] = h ? s1_ : wdp_[a0_ + 1];                                       \
        pb4_[2] = h ? wdp_[a0_] : s0_;                                           \
        pb4_[3] = h ? wdp_[a0_ + 1] : s1_;                                       \
        bf16x8 pb_ = __builtin_bit_cast(bf16x8, *(uint4*)pb4_);                  \
        int cb_ = ((t4 * 32) ^ vxor) >> 1;                                       \
        _Pragma("unroll")                                                        \
        for (int n = 0; n < 4; ++n) {                                            \
          bf16x8 va_ = *(const bf16x8*)(Vbuf_ + (size_t)(32 * n + l31) * 64 + cb_); \
          ot[n] = __builtin_amdgcn_mfma_f32_32x32x16_bf16(va_, pb_, ot[n], 0, 0, 0); \
        }                                                                        \
      }                                                                          \
    }                                                                            \
    asm volatile("s_waitcnt vmcnt(0)" ::: "memory");                             \
    __builtin_amdgcn_s_barrier();                                                \
    __builtin_amdgcn_sched_barrier(0);                                           \
  }

__global__ __launch_bounds__(256, 2) void flash_attn_k(
    const bf16* __restrict__ Q, const bf16* __restrict__ Kb,
    const bf16* __restrict__ Vt, bf16* __restrict__ O) {
  __shared__ bf16 sh[32768];  // elems: K0 @0, K1 @8192, V0 @16384, V1 @24576
  const int tid = threadIdx.x;
  const int lane = tid & 63;
  const int w = tid >> 6;
  const int h = lane >> 5;
  const int l31 = lane & 31;
  const int bh = blockIdx.y;
  const int b = bh >> 4;
  const int hh = bh & 15;
  const int qb = (gridDim.x - 1 - blockIdx.x) * 128;  // long blocks first
  const int qw0 = qb + 32 * w;
  const int q = qw0 + l31;

  const bf16* qp = Q + (size_t)(b * S_LEN + q) * QKV_STR + hh * HD + h * 8;
  bf16x8 qf[8];
#pragma unroll
  for (int ks = 0; ks < 8; ++ks) qf[ks] = *(const bf16x8*)(qp + ks * 16);

  f32x16 ot[4] = {};
  float m_run = -3.0e38f, l_run = 0.f;

  const bf16* Kg = Kb + (size_t)(b * S_LEN) * QKV_STR + hh * HD;
  const bf16* Vg = Vt + (size_t)bh * HD * S_LEN;

  const int kst_row = 16 * w + (lane >> 4);
  const int vst_row = 32 * w + (lane >> 3);
  const int vst_col = (((lane & 7) ^ (lane >> 3)) << 3);
  const int kxor = (16 * h) ^ ((l31 & 15) << 4);
  const int vxor = (16 * h) ^ ((l31 & 7) << 4);

  auto stageK = [&](int kv0, int buf) {
#pragma unroll
    for (int jj = 0; jj < 4; ++jj) {
      int kr = (kv0 + kst_row + jj * 4) & (S_LEN - 1);
      gload16(Kg + (size_t)kr * QKV_STR + (((lane & 15) ^ (jj * 4 + (lane >> 4))) << 3),
              &sh[buf * 8192 + (16 * w + jj * 4) * 128]);
    }
  };
  auto stageV = [&](int kv0, int buf) {
    int c = (kv0 & (S_LEN - 1)) + vst_col;
#pragma unroll
    for (int jj = 0; jj < 4; ++jj) {
      int vr = vst_row + jj * 8;
      gload16(Vg + (size_t)vr * S_LEN + c, &sh[16384 + buf * 8192 + (32 * w + jj * 8) * 64]);
    }
  };

  // prologue: K(0), V(0), K(1); QK(0) -> stA
  stageK(0, 0);
  stageV(0, 0);
  stageK(64, 1);
  asm volatile("s_waitcnt vmcnt(8)" ::: "memory");  // K(0) landed
  __builtin_amdgcn_s_barrier();
  __builtin_amdgcn_sched_barrier(0);

  f32x16 stA0 = 0.0f, stA1 = 0.0f, stB0, stB1;
  {
    const bf16* krow0 = &sh[0] + (size_t)l31 * 128;
    const bf16* krow1 = krow0 + 32 * 128;
#pragma unroll
    for (int ks = 0; ks < 8; ++ks) {
      int cb = ((ks * 32) ^ kxor) >> 1;
      bf16x8 kf0 = *(const bf16x8*)(krow0 + cb);
      bf16x8 kf1 = *(const bf16x8*)(krow1 + cb);
      stA0 = __builtin_amdgcn_mfma_f32_32x32x16_bf16(kf0, qf[ks], stA0, 0, 0, 0);
      stA1 = __builtin_amdgcn_mfma_f32_32x32x16_bf16(kf1, qf[ks], stA1, 0, 0, 0);
    }
  }
  asm volatile("s_waitcnt vmcnt(0)" ::: "memory");  // V(0), K(1) landed
  __builtin_amdgcn_s_barrier();
  __builtin_amdgcn_sched_barrier(0);

  const int nt = qb / 64 + 2;
  int t = 0;
  for (; t + 1 < nt; t += 2) {
    FBODY(t, stA0, stA1, stB0, stB1);
    FBODY(t + 1, stB0, stB1, stA0, stA1);
  }
  if (t < nt) FBODY(t, stA0, stA1, stB0, stB1);

  // epilogue: O^T -> LDS (swizzled) -> coalesced global
  float inv = 1.0f / l_run;
  bf16* ow = &sh[w * 4096];  // 32 rows x 128 cols per wave
#pragma unroll
  for (int n = 0; n < 4; ++n)
#pragma unroll
    for (int rq = 0; rq < 4; ++rq) {
      int dbase = 32 * n + 8 * rq + 4 * h;
      unsigned u0 = cvtpk(ot[n][4 * rq + 0] * inv, ot[n][4 * rq + 1] * inv);
      unsigned u1 = cvtpk(ot[n][4 * rq + 2] * inv, ot[n][4 * rq + 3] * inv);
      uint2 uu = make_uint2(u0, u1);
      *(uint2*)(ow + l31 * 128 + (dbase ^ ((l31 & 15) << 3))) = uu;
    }
  __syncthreads();
#pragma unroll
  for (int p = 0; p < 8; ++p) {
    int qr = p * 4 + (lane >> 4);
    int ce = ((((lane & 15) << 4) ^ ((qr & 15) << 4)) >> 1);
    bf16x8 vrow = *(const bf16x8*)(ow + qr * 128 + ce);
    *(bf16x8*)(O + (size_t)(b * S_LEN + qw0 + qr) * D_DIM + hh * HD + (lane & 15) * 8) = vrow;
  }
}

// ---------------- launch ----------------

extern "C" void kernel_launch(void* const* d_in, const int* in_sizes, int n_in,
                              void* d_out, int out_size, void* d_ws, size_t ws_size,
                              hipStream_t stream) {
  (void)in_sizes; (void)n_in; (void)out_size; (void)ws_size;
  const float* x  = (const float*)d_in[0];
  const float* wq = (const float*)d_in[1];
  const float* wk = (const float*)d_in[2];
  const float* wv = (const float*)d_in[3];
  const float* wo = (const float*)d_in[4];
  float* out = (float*)d_out;

  char* ws = (char*)d_ws;
  const size_t MB = 1u << 20;
  bf16* xb    = (bf16*)(ws + 0 * MB);    // 16MB; reused as O after attention
  bf16* Ob    = xb;
  bf16* wTall = (bf16*)(ws + 16 * MB);   // 24MB: wq^T | wk^T | wv^T rows
  bf16* wTo   = (bf16*)(ws + 40 * MB);   // 8MB
  bf16* QKV   = (bf16*)(ws + 48 * MB);   // 48MB: [4096][6144]
  bf16* Vtb   = (bf16*)(ws + 96 * MB);   // 16MB
  float2* tab = (float2*)(ws + 112 * MB);

  rope_table_k<<<512, 256, 0, stream>>>(tab);
  convert_x_k<<<8192, 256, 0, stream>>>(x, xb);
  dim3 tg(32, 32);
  transpose_w_k<<<tg, 256, 0, stream>>>(wq, wTall);
  transpose_w_k<<<tg, 256, 0, stream>>>(wk, wTall + (size_t)2048 * D_DIM);
  transpose_w_k<<<tg, 256, 0, stream>>>(wv, wTall + (size_t)4096 * D_DIM);
  transpose_w_k<<<tg, 256, 0, stream>>>(wo, wTo);

  // fused QKV projection: [4096][2048] @ [6144][2048]^T -> [4096][6144]
  gemm_bt_k<bf16><<<dim3(QKV_STR / 128, NROW / 128), 256, 0, stream>>>(
      xb, wTall, QKV, NROW, QKV_STR, D_DIM);

  rope_apply_k<<<16384, 256, 0, stream>>>(QKV, tab);
  transpose_v_k<<<dim3(32, 2, 32), 256, 0, stream>>>(QKV + 4096, Vtb);

  flash_attn_k<<<dim3(S_LEN / 128, NB * NH), 256, 0, stream>>>(
      QKV, QKV + 2048, Vtb, Ob);

  gemm_bt_k<float><<<dim3(D_DIM / 128, NROW / 128), 256, 0, stream>>>(
      Ob, wTo, out, NROW, D_DIM, D_DIM);
}